// Round 1
// baseline (604.647 us; speedup 1.0000x reference)
//
#include <hip/hip_runtime.h>
#include <math.h>

#define BB 2
#define NN 2048
#define DD 512
#define HH 8
#define HD 64
#define KML 1000

typedef long long i64;
typedef unsigned short u16;
typedef __attribute__((ext_vector_type(8))) short bf16x8;
typedef __attribute__((ext_vector_type(16))) float f32x16;

__device__ __forceinline__ u16 f2bf(float x) {
    unsigned int u = __float_as_uint(x);
    u += 0x7FFFu + ((u >> 16) & 1u);
    return (u16)(u >> 16);
}

// ---------------------------------------------------------------------------
// fp32 SGEMM: C[M,N] = A @ B + bias.  64x64 tiles, BK=16, 256 thr, 4x4 micro.
// ATRANS: A is [K,M].  BIAS_ROW: bias indexed by m.  BF16OUT: store bf16.
// ---------------------------------------------------------------------------
template<bool ATRANS, bool BIAS_ROW, bool BF16OUT>
__global__ __launch_bounds__(256) void sgemm64(
    const float* __restrict__ A, const float* __restrict__ Bm,
    const float* __restrict__ bias, void* __restrict__ Cout,
    int M, int N, int K)
{
    __shared__ float As[16][68];   // [k][m]
    __shared__ float Bs[16][68];   // [k][n]
    const int t  = threadIdx.x;
    const int tx = t & 15, ty = t >> 4;
    const int m0 = blockIdx.y * 64, n0 = blockIdx.x * 64;

    float acc[4][4];
#pragma unroll
    for (int i = 0; i < 4; ++i)
#pragma unroll
        for (int j = 0; j < 4; ++j) acc[i][j] = 0.f;

    for (int k0 = 0; k0 < K; k0 += 16) {
        __syncthreads();
        if (!ATRANS) {
            int m = t >> 2, k4 = t & 3;                 // 64 x 4-float4
            float4 v = *((const float4*)(A + (i64)(m0 + m) * K + k0) + k4);
            As[k4 * 4 + 0][m] = v.x; As[k4 * 4 + 1][m] = v.y;
            As[k4 * 4 + 2][m] = v.z; As[k4 * 4 + 3][m] = v.w;
        } else {
            int k = t >> 4, m4 = t & 15;                // 16 x 16-float4
            float4 v;
            if (k0 + k < K) v = *((const float4*)(A + (i64)(k0 + k) * M + m0) + m4);
            else            v = make_float4(0.f, 0.f, 0.f, 0.f);
            As[k][m4 * 4 + 0] = v.x; As[k][m4 * 4 + 1] = v.y;
            As[k][m4 * 4 + 2] = v.z; As[k][m4 * 4 + 3] = v.w;
        }
        {
            int k = t >> 4, n4 = t & 15;
            float4 v;
            if (k0 + k < K) v = *((const float4*)(Bm + (i64)(k0 + k) * N + n0) + n4);
            else            v = make_float4(0.f, 0.f, 0.f, 0.f);
            Bs[k][n4 * 4 + 0] = v.x; Bs[k][n4 * 4 + 1] = v.y;
            Bs[k][n4 * 4 + 2] = v.z; Bs[k][n4 * 4 + 3] = v.w;
        }
        __syncthreads();
#pragma unroll
        for (int k = 0; k < 16; ++k) {
            float4 a = *(const float4*)&As[k][ty * 4];
            float4 b = *(const float4*)&Bs[k][tx * 4];
            float av[4] = {a.x, a.y, a.z, a.w};
            float bv[4] = {b.x, b.y, b.z, b.w};
#pragma unroll
            for (int i = 0; i < 4; ++i)
#pragma unroll
                for (int j = 0; j < 4; ++j) acc[i][j] = fmaf(av[i], bv[j], acc[i][j]);
        }
    }
#pragma unroll
    for (int i = 0; i < 4; ++i) {
        int m = m0 + ty * 4 + i;
        float4 o;
        if (BIAS_ROW) {
            float bv = bias[m];
            o = make_float4(acc[i][0] + bv, acc[i][1] + bv, acc[i][2] + bv, acc[i][3] + bv);
        } else {
            const float* bp = bias + n0 + tx * 4;
            o = make_float4(acc[i][0] + bp[0], acc[i][1] + bp[1],
                            acc[i][2] + bp[2], acc[i][3] + bp[3]);
        }
        if (BF16OUT) {
            u16* C = (u16*)Cout;
            ushort4 ob = make_ushort4(f2bf(o.x), f2bf(o.y), f2bf(o.z), f2bf(o.w));
            *((ushort4*)(C + (i64)m * N + n0 + tx * 4)) = ob;
        } else {
            float* C = (float*)Cout;
            *((float4*)(C + (i64)m * N + n0 + tx * 4)) = o;
        }
    }
}

// ---------------------------------------------------------------------------
// Fused flash-style attention with P materialization (P is a required output).
// Per block: one 32-row strip of one (b,h).  4 waves split the 2048 columns
// (interleaved 32-col chunks).  32x32x16 bf16 MFMA.
// Phase 1: S = QK^T/8 (MFMA), accumulate per-row sum(exp2(S*log2e)) -- no max
//          subtraction needed (|S| <~ 1.5, softmax is shift-invariant).
// Phase 2: recompute S, p = exp2(S*log2e) * (1/L), store P fp32 (coalesced),
//          stage p->bf16 via per-wave LDS tile (C-layout -> A-layout), MFMA PV.
// Cross-wave O reduction via LDS.  1D grid with XCD swizzle (1024 % 8 == 0).
// ---------------------------------------------------------------------------
__global__ __launch_bounds__(256, 2) void attn_fused(
    const u16* __restrict__ qbf,   // [4096][512] bf16 (b-major rows)
    const u16* __restrict__ kbf,   // [4096][512] bf16
    const u16* __restrict__ vTb,   // [512][2048] bf16  (d-major: vT[d][j])
    float* __restrict__ attn,      // [16][2048][2048] fp32
    float* __restrict__ hout)      // [2][2048][512] fp32
{
    __shared__ u16   Plds[4][32][40];   // per-wave P tile, row stride 80B (16B-mult)
    __shared__ float redL[4][32];
    __shared__ float ilsh[32];
    __shared__ float Olds[4][64][36];   // [wave][d][row], stride 144B

    const int t    = threadIdx.x;
    const int lane = t & 63;
    const int w    = t >> 6;
    const int l31  = lane & 31;
    const int h5   = lane >> 5;         // 0/1

    // XCD swizzle: 1024 blocks, 8 XCDs -> each XCD gets 2 consecutive (b,h)
    const int bid = blockIdx.x;
    const int swz = (bid & 7) * 128 + (bid >> 3);
    const int bx  = swz & 63;           // row-strip index
    const int bh  = swz >> 6;           // (b,h)
    const int b   = bh >> 3, h = bh & 7;
    const int i0  = bx * 32;
    const float SC = 0.18033688011112042f;   // 0.125 * log2(e)

    const u16* qb = qbf + (i64)(b * NN + i0) * DD + h * HD;
    const u16* kb = kbf + (i64)(b * NN) * DD + h * HD;
    const u16* vb = vTb + (i64)h * HD * NN;
    float* Pg = attn + (i64)bh * NN * NN;

    int roff[16];
#pragma unroll
    for (int r = 0; r < 16; ++r) roff[r] = (r & 3) + 8 * (r >> 2) + 4 * h5;

    // ---- Q fragments: A[i][k], lane holds row l31, k = 16f + 8*h5 + (0..7) ----
    bf16x8 qa[4];
#pragma unroll
    for (int f = 0; f < 4; ++f)
        qa[f] = *(const bf16x8*)(qb + (i64)l31 * DD + f * 16 + h5 * 8);

    // ================= phase 1: row sums =================
    float lsum[16];
#pragma unroll
    for (int r = 0; r < 16; ++r) lsum[r] = 0.f;

    for (int c = 0; c < 16; ++c) {
        const int j0 = (c * 4 + w) * 32;
        bf16x8 kf[4];
#pragma unroll
        for (int f = 0; f < 4; ++f)
            kf[f] = *(const bf16x8*)(kb + (i64)(j0 + l31) * DD + f * 16 + h5 * 8);
        f32x16 s;
#pragma unroll
        for (int r = 0; r < 16; ++r) s[r] = 0.f;
#pragma unroll
        for (int f = 0; f < 4; ++f)
            s = __builtin_amdgcn_mfma_f32_32x32x16_bf16(qa[f], kf[f], s, 0, 0, 0);
        const int gj = j0 + l31;
#pragma unroll
        for (int r = 0; r < 16; ++r) {
            int d = (i0 + roff[r]) - gj;
            float e = (d >= -3 && d <= 3) ? 0.f
                    : __builtin_amdgcn_exp2f(s[r] * SC);
            lsum[r] += e;
        }
    }
    // reduce across the 32 column-lanes of each half-wave
#pragma unroll
    for (int r = 0; r < 16; ++r) {
        float v = lsum[r];
        v += __shfl_xor(v, 1);
        v += __shfl_xor(v, 2);
        v += __shfl_xor(v, 4);
        v += __shfl_xor(v, 8);
        v += __shfl_xor(v, 16);
        lsum[r] = v;
    }
    if (l31 == 0) {
#pragma unroll
        for (int r = 0; r < 16; ++r) redL[w][roff[r]] = lsum[r];
    }
    __syncthreads();
    if (t < 32) ilsh[t] = 1.f / (redL[0][t] + redL[1][t] + redL[2][t] + redL[3][t]);
    __syncthreads();
    float ilv[16];
#pragma unroll
    for (int r = 0; r < 16; ++r) ilv[r] = ilsh[roff[r]];

    // ================= phase 2: P store + PV =================
    f32x16 oacc[2];
#pragma unroll
    for (int dt = 0; dt < 2; ++dt)
#pragma unroll
        for (int r = 0; r < 16; ++r) oacc[dt][r] = 0.f;

    for (int c = 0; c < 16; ++c) {
        const int j0 = (c * 4 + w) * 32;
        bf16x8 kf[4];
#pragma unroll
        for (int f = 0; f < 4; ++f)
            kf[f] = *(const bf16x8*)(kb + (i64)(j0 + l31) * DD + f * 16 + h5 * 8);
        f32x16 s;
#pragma unroll
        for (int r = 0; r < 16; ++r) s[r] = 0.f;
#pragma unroll
        for (int f = 0; f < 4; ++f)
            s = __builtin_amdgcn_mfma_f32_32x32x16_bf16(qa[f], kf[f], s, 0, 0, 0);
        const int gj = j0 + l31;
#pragma unroll
        for (int r = 0; r < 16; ++r) {
            int gi = i0 + roff[r];
            int d  = gi - gj;
            float p = (d >= -3 && d <= 3) ? 0.f
                    : __builtin_amdgcn_exp2f(s[r] * SC) * ilv[r];
            Pg[(i64)gi * NN + gj] = p;                 // two full 128B segs/instr
            Plds[w][roff[r]][l31] = f2bf(p);
        }
        // PV: A = P rows (from LDS), B = V (d-major, contiguous in j)
#pragma unroll
        for (int jt = 0; jt < 2; ++jt) {
            bf16x8 pa = *(const bf16x8*)&Plds[w][l31][jt * 16 + h5 * 8];
#pragma unroll
            for (int dt = 0; dt < 2; ++dt) {
                bf16x8 vf = *(const bf16x8*)(vb + (i64)(dt * 32 + l31) * NN
                                             + j0 + jt * 16 + h5 * 8);
                oacc[dt] = __builtin_amdgcn_mfma_f32_32x32x16_bf16(pa, vf, oacc[dt], 0, 0, 0);
            }
        }
    }

    // ---- cross-wave O reduction ----
#pragma unroll
    for (int dt = 0; dt < 2; ++dt) {
        const int d = dt * 32 + l31;
#pragma unroll
        for (int g = 0; g < 4; ++g) {
            float4 o4 = make_float4(oacc[dt][g * 4 + 0], oacc[dt][g * 4 + 1],
                                    oacc[dt][g * 4 + 2], oacc[dt][g * 4 + 3]);
            *(float4*)&Olds[w][d][g * 8 + 4 * h5] = o4;
        }
    }
    __syncthreads();
#pragma unroll
    for (int it = 0; it < 8; ++it) {
        int d = t & 63, row = (t >> 6) + it * 4;
        float v = Olds[0][d][row] + Olds[1][d][row]
                + Olds[2][d][row] + Olds[3][d][row];
        hout[(i64)(b * NN + i0 + row) * DD + h * HD + d] = v;
    }
}

// ---------------------------------------------------------------------------
extern "C" void kernel_launch(void* const* d_in, const int* in_sizes, int n_in,
                              void* d_out, int out_size, void* d_ws, size_t ws_size,
                              hipStream_t stream)
{
    const float* q    = (const float*)d_in[0];
    const float* k    = (const float*)d_in[1];
    const float* Wq   = (const float*)d_in[3];
    const float* bq   = (const float*)d_in[4];
    const float* Wk   = (const float*)d_in[5];
    const float* bk   = (const float*)d_in[6];
    const float* Vemb = (const float*)d_in[7];
    const float* Wv2  = (const float*)d_in[8];
    const float* bv2  = (const float*)d_in[9];
    const float* Wout = (const float*)d_in[10];
    const float* bout = (const float*)d_in[11];

    float* outp = (float*)d_out;                   // [2,2048,512]
    float* attn = outp + (i64)BB * NN * DD;        // [2,8,2048,2048]

    u16* qbf = (u16*)d_ws;                         // 4096*512 bf16 = 4 MB
    u16* kbf = qbf + (i64)4096 * 512;              // 4 MB
    u16* vTb = kbf + (i64)4096 * 512;              // [512][2048] bf16 = 2 MB
    float* hout = (float*)(vTb + (i64)512 * 2048); // 8 MB (offset 16B-aligned)

    // qp = q@Wq+bq  -> bf16 [4096][512]
    sgemm64<false, false, true ><<<dim3(8, 64), 256, 0, stream>>>(q, Wq, bq, qbf, 4096, 512, 512);
    // kp = k@Wk+bk  -> bf16 [4096][512]
    sgemm64<false, false, true ><<<dim3(8, 64), 256, 0, stream>>>(k, Wk, bk, kbf, 4096, 512, 512);
    // vT[d][s] = sum_m Vemb[m][d]*Wv2[m][s] + bv2[s]  -> bf16 [512][2048]
    sgemm64<true,  false, true ><<<dim3(32, 8), 256, 0, stream>>>(Vemb, Wv2, bv2, vTb, 512, 2048, KML);
    // fused attention: writes attn (fp32 P) + hout
    attn_fused<<<dim3(1024), 256, 0, stream>>>(qbf, kbf, vTb, attn, hout);
    // out = hout@Wout + bout
    sgemm64<false, false, false><<<dim3(8, 64), 256, 0, stream>>>(hout, Wout, bout, outp, 4096, 512, 512);
}

// Round 2
// 453.604 us; speedup vs baseline: 1.3330x; 1.3330x over previous
//
#include <hip/hip_runtime.h>
#include <math.h>

#define BB 2
#define NN 2048
#define DD 512
#define HH 8
#define HD 64
#define KML 1000

typedef long long i64;
typedef unsigned short u16;
typedef __attribute__((ext_vector_type(8))) short bf16x8;
typedef __attribute__((ext_vector_type(16))) float f32x16;

__device__ __forceinline__ u16 f2bf(float x) {
    unsigned int u = __float_as_uint(x);
    u += 0x7FFFu + ((u >> 16) & 1u);
    return (u16)(u >> 16);
}

// ---------------------------------------------------------------------------
// Transpose-cast prepass: out[n][kp] = bf16(in[k][n]), zero-pad k >= K.
// One launch handles all 5 weight tensors via blockIdx.z.
// ---------------------------------------------------------------------------
__global__ __launch_bounds__(256) void tcast5(
    const float* __restrict__ w0, const float* __restrict__ w1,
    const float* __restrict__ w2, const float* __restrict__ w3,
    const float* __restrict__ w4,
    u16* __restrict__ o0, u16* __restrict__ o1, u16* __restrict__ o2,
    u16* __restrict__ o3, u16* __restrict__ o4)
{
    const float* in; u16* out; int K, N, Kp;
    switch (blockIdx.z) {
        case 0: in = w0; out = o0; K = 512;  N = 512;  Kp = 512;  break;
        case 1: in = w1; out = o1; K = 512;  N = 512;  Kp = 512;  break;
        case 2: in = w2; out = o2; K = 512;  N = 512;  Kp = 512;  break;
        case 3: in = w3; out = o3; K = 1000; N = 2048; Kp = 1024; break;
        default:in = w4; out = o4; K = 1000; N = 512;  Kp = 1024; break;
    }
    const int n0 = blockIdx.x * 32, kp0 = blockIdx.y * 32;
    if (n0 >= N || kp0 >= Kp) return;
    __shared__ float ld[32][33];
    const int t = threadIdx.x, tx = t & 31, ty = t >> 5;
#pragma unroll
    for (int i = 0; i < 4; ++i) {
        int kk = kp0 + ty + i * 8;
        ld[ty + i * 8][tx] = (kk < K) ? in[(i64)kk * N + n0 + tx] : 0.f;
    }
    __syncthreads();
#pragma unroll
    for (int i = 0; i < 4; ++i)
        out[(i64)(n0 + ty + i * 8) * Kp + kp0 + tx] = f2bf(ld[tx][ty + i * 8]);
}

// ---------------------------------------------------------------------------
// bf16 MFMA GEMM: C[M,N] = A[M,K] @ BT[N,K]^T + bias[n].
// A fp32 (cast on stage) or bf16.  BT bf16 (pre-transposed weights).
// Tile 64x128, BK=32, 256 thr = 4 waves in 2x2, wave tile 32x64,
// 32x32x16 bf16 MFMA.  LDS rows padded to 40 u16 (80B) -> <=4-way conflict.
// ---------------------------------------------------------------------------
template<bool AF32, bool BF16OUT>
__global__ __launch_bounds__(256) void mgemm(
    const void* __restrict__ Ap, const u16* __restrict__ BT,
    const float* __restrict__ bias, void* __restrict__ Cout,
    int M, int N, int K)
{
    __shared__ u16 Asl[64][40];
    __shared__ u16 Bsl[128][40];
    const int t = threadIdx.x;
    const int lane = t & 63, w = t >> 6;
    const int l31 = lane & 31, h5 = lane >> 5;
    const int wm = w >> 1, wn = w & 1;
    const int m0 = blockIdx.y * 64, n0 = blockIdx.x * 128;

    int roff[16];
#pragma unroll
    for (int r = 0; r < 16; ++r) roff[r] = (r & 3) + 8 * (r >> 2) + 4 * h5;

    f32x16 acc[2];
#pragma unroll
    for (int nt = 0; nt < 2; ++nt)
#pragma unroll
        for (int r = 0; r < 16; ++r) acc[nt][r] = 0.f;

    for (int k0 = 0; k0 < K; k0 += 32) {
        __syncthreads();
        {   // A tile: 64 x 32
            int row = t >> 2, kc = (t & 3) * 8;
            if (AF32) {
                const float* A = (const float*)Ap;
                const float* src = A + (i64)(m0 + row) * K + k0 + kc;
                float4 v0 = *(const float4*)src;
                float4 v1 = *(const float4*)(src + 4);
                bf16x8 p;
                p[0] = (short)f2bf(v0.x); p[1] = (short)f2bf(v0.y);
                p[2] = (short)f2bf(v0.z); p[3] = (short)f2bf(v0.w);
                p[4] = (short)f2bf(v1.x); p[5] = (short)f2bf(v1.y);
                p[6] = (short)f2bf(v1.z); p[7] = (short)f2bf(v1.w);
                *(bf16x8*)&Asl[row][kc] = p;
            } else {
                const u16* A = (const u16*)Ap;
                *(bf16x8*)&Asl[row][kc] =
                    *(const bf16x8*)(A + (i64)(m0 + row) * K + k0 + kc);
            }
        }
        {   // B tile: 128 x 32 (bf16, k-contiguous)
            int row = t >> 1, kc = (t & 1) * 16;
            const u16* src = BT + (i64)(n0 + row) * K + k0 + kc;
            *(bf16x8*)&Bsl[row][kc]     = *(const bf16x8*)src;
            *(bf16x8*)&Bsl[row][kc + 8] = *(const bf16x8*)(src + 8);
        }
        __syncthreads();
#pragma unroll
        for (int kk = 0; kk < 2; ++kk) {
            bf16x8 af = *(const bf16x8*)&Asl[wm * 32 + l31][kk * 16 + h5 * 8];
#pragma unroll
            for (int nt = 0; nt < 2; ++nt) {
                bf16x8 bf = *(const bf16x8*)&Bsl[wn * 64 + nt * 32 + l31][kk * 16 + h5 * 8];
                acc[nt] = __builtin_amdgcn_mfma_f32_32x32x16_bf16(af, bf, acc[nt], 0, 0, 0);
            }
        }
    }
#pragma unroll
    for (int nt = 0; nt < 2; ++nt) {
        int col = n0 + wn * 64 + nt * 32 + l31;
        float bv = bias[col];
#pragma unroll
        for (int r = 0; r < 16; ++r) {
            int row = m0 + wm * 32 + roff[r];
            float v = acc[nt][r] + bv;
            if (BF16OUT) ((u16*)Cout)[(i64)row * N + col] = f2bf(v);
            else         ((float*)Cout)[(i64)row * N + col] = v;
        }
    }
}

// ---------------------------------------------------------------------------
// Fused flash-style attention with P materialization (P is a required output).
// Per block: one 32-row strip of one (b,h).  4 waves split the 2048 columns
// (interleaved 32-col chunks).  32x32x16 bf16 MFMA.
// Phase 1: S = QK^T/8 (MFMA), accumulate per-row sum(exp2(S*log2e)) -- no max
//          subtraction needed (|S| <~ 1.5, softmax is shift-invariant).
// Phase 2: recompute S, p = exp2(S*log2e) * (1/L), store P fp32 (coalesced),
//          stage p->bf16 via per-wave LDS tile (C-layout -> A-layout), MFMA PV.
// Band mask applied only in chunks overlapping the diagonal (wave-uniform).
// ---------------------------------------------------------------------------
__global__ __launch_bounds__(256, 2) void attn_fused(
    const u16* __restrict__ qbf,   // [4096][512] bf16
    const u16* __restrict__ kbf,   // [4096][512] bf16
    const u16* __restrict__ vTb,   // [512][2048] bf16  (d-major: vT[d][j])
    float* __restrict__ attn,      // [16][2048][2048] fp32
    float* __restrict__ hout)      // [2][2048][512] fp32
{
    __shared__ u16   Plds[4][32][40];
    __shared__ float redL[4][32];
    __shared__ float ilsh[32];
    __shared__ float Olds[4][64][36];

    const int t    = threadIdx.x;
    const int lane = t & 63;
    const int w    = t >> 6;
    const int l31  = lane & 31;
    const int h5   = lane >> 5;

    const int bid = blockIdx.x;
    const int swz = (bid & 7) * 128 + (bid >> 3);
    const int bx  = swz & 63;
    const int bh  = swz >> 6;
    const int b   = bh >> 3, h = bh & 7;
    const int i0  = bx * 32;
    const float SC = 0.18033688011112042f;   // 0.125 * log2(e)

    const u16* qb = qbf + (i64)(b * NN + i0) * DD + h * HD;
    const u16* kb = kbf + (i64)(b * NN) * DD + h * HD;
    const u16* vb = vTb + (i64)h * HD * NN;
    float* Pg = attn + (i64)bh * NN * NN;

    int roff[16];
#pragma unroll
    for (int r = 0; r < 16; ++r) roff[r] = (r & 3) + 8 * (r >> 2) + 4 * h5;

    bf16x8 qa[4];
#pragma unroll
    for (int f = 0; f < 4; ++f)
        qa[f] = *(const bf16x8*)(qb + (i64)l31 * DD + f * 16 + h5 * 8);

    // ================= phase 1: row sums =================
    float lsum[16];
#pragma unroll
    for (int r = 0; r < 16; ++r) lsum[r] = 0.f;

    for (int c = 0; c < 16; ++c) {
        const int j0 = (c * 4 + w) * 32;
        bf16x8 kf[4];
#pragma unroll
        for (int f = 0; f < 4; ++f)
            kf[f] = *(const bf16x8*)(kb + (i64)(j0 + l31) * DD + f * 16 + h5 * 8);
        f32x16 s;
#pragma unroll
        for (int r = 0; r < 16; ++r) s[r] = 0.f;
#pragma unroll
        for (int f = 0; f < 4; ++f)
            s = __builtin_amdgcn_mfma_f32_32x32x16_bf16(qa[f], kf[f], s, 0, 0, 0);
        const int gj = j0 + l31;
        const bool hasband = (j0 >= i0 - 34) && (j0 <= i0 + 34);
        if (hasband) {
#pragma unroll
            for (int r = 0; r < 16; ++r) {
                int d = (i0 + roff[r]) - gj;
                float e = (d >= -3 && d <= 3) ? 0.f
                        : __builtin_amdgcn_exp2f(s[r] * SC);
                lsum[r] += e;
            }
        } else {
#pragma unroll
            for (int r = 0; r < 16; ++r)
                lsum[r] += __builtin_amdgcn_exp2f(s[r] * SC);
        }
    }
#pragma unroll
    for (int r = 0; r < 16; ++r) {
        float v = lsum[r];
        v += __shfl_xor(v, 1);
        v += __shfl_xor(v, 2);
        v += __shfl_xor(v, 4);
        v += __shfl_xor(v, 8);
        v += __shfl_xor(v, 16);
        lsum[r] = v;
    }
    if (l31 == 0) {
#pragma unroll
        for (int r = 0; r < 16; ++r) redL[w][roff[r]] = lsum[r];
    }
    __syncthreads();
    if (t < 32) ilsh[t] = 1.f / (redL[0][t] + redL[1][t] + redL[2][t] + redL[3][t]);
    __syncthreads();
    float ilv[16];
#pragma unroll
    for (int r = 0; r < 16; ++r) ilv[r] = ilsh[roff[r]];

    // ================= phase 2: P store + PV =================
    f32x16 oacc[2];
#pragma unroll
    for (int dt = 0; dt < 2; ++dt)
#pragma unroll
        for (int r = 0; r < 16; ++r) oacc[dt][r] = 0.f;

    for (int c = 0; c < 16; ++c) {
        const int j0 = (c * 4 + w) * 32;
        bf16x8 kf[4];
#pragma unroll
        for (int f = 0; f < 4; ++f)
            kf[f] = *(const bf16x8*)(kb + (i64)(j0 + l31) * DD + f * 16 + h5 * 8);
        f32x16 s;
#pragma unroll
        for (int r = 0; r < 16; ++r) s[r] = 0.f;
#pragma unroll
        for (int f = 0; f < 4; ++f)
            s = __builtin_amdgcn_mfma_f32_32x32x16_bf16(qa[f], kf[f], s, 0, 0, 0);
        const int gj = j0 + l31;
        const bool hasband = (j0 >= i0 - 34) && (j0 <= i0 + 34);
        if (hasband) {
#pragma unroll
            for (int r = 0; r < 16; ++r) {
                int gi = i0 + roff[r];
                int d  = gi - gj;
                float p = (d >= -3 && d <= 3) ? 0.f
                        : __builtin_amdgcn_exp2f(s[r] * SC) * ilv[r];
                Pg[(i64)gi * NN + gj] = p;
                Plds[w][roff[r]][l31] = f2bf(p);
            }
        } else {
#pragma unroll
            for (int r = 0; r < 16; ++r) {
                int gi = i0 + roff[r];
                float p = __builtin_amdgcn_exp2f(s[r] * SC) * ilv[r];
                Pg[(i64)gi * NN + gj] = p;
                Plds[w][roff[r]][l31] = f2bf(p);
            }
        }
#pragma unroll
        for (int jt = 0; jt < 2; ++jt) {
            bf16x8 pa = *(const bf16x8*)&Plds[w][l31][jt * 16 + h5 * 8];
#pragma unroll
            for (int dt = 0; dt < 2; ++dt) {
                bf16x8 vf = *(const bf16x8*)(vb + (i64)(dt * 32 + l31) * NN
                                             + j0 + jt * 16 + h5 * 8);
                oacc[dt] = __builtin_amdgcn_mfma_f32_32x32x16_bf16(pa, vf, oacc[dt], 0, 0, 0);
            }
        }
    }

    // ---- cross-wave O reduction ----
#pragma unroll
    for (int dt = 0; dt < 2; ++dt) {
        const int d = dt * 32 + l31;
#pragma unroll
        for (int g = 0; g < 4; ++g) {
            float4 o4 = make_float4(oacc[dt][g * 4 + 0], oacc[dt][g * 4 + 1],
                                    oacc[dt][g * 4 + 2], oacc[dt][g * 4 + 3]);
            *(float4*)&Olds[w][d][g * 8 + 4 * h5] = o4;
        }
    }
    __syncthreads();
#pragma unroll
    for (int it = 0; it < 8; ++it) {
        int d = t & 63, row = (t >> 6) + it * 4;
        float v = Olds[0][d][row] + Olds[1][d][row]
                + Olds[2][d][row] + Olds[3][d][row];
        hout[(i64)(b * NN + i0 + row) * DD + h * HD + d] = v;
    }
}

// ---------------------------------------------------------------------------
extern "C" void kernel_launch(void* const* d_in, const int* in_sizes, int n_in,
                              void* d_out, int out_size, void* d_ws, size_t ws_size,
                              hipStream_t stream)
{
    const float* q    = (const float*)d_in[0];
    const float* k    = (const float*)d_in[1];
    const float* Wq   = (const float*)d_in[3];
    const float* bq   = (const float*)d_in[4];
    const float* Wk   = (const float*)d_in[5];
    const float* bk   = (const float*)d_in[6];
    const float* Vemb = (const float*)d_in[7];
    const float* Wv2  = (const float*)d_in[8];
    const float* bv2  = (const float*)d_in[9];
    const float* Wout = (const float*)d_in[10];
    const float* bout = (const float*)d_in[11];

    float* outp = (float*)d_out;                   // [2,2048,512]
    float* attn = outp + (i64)BB * NN * DD;        // [2,8,2048,2048]

    u16* qbf   = (u16*)d_ws;                       // 4 MB
    u16* kbf   = qbf + (i64)4096 * 512;            // 4 MB
    u16* vTb   = kbf + (i64)4096 * 512;            // [512][2048] = 2 MB
    float* hout = (float*)(vTb + (i64)512 * 2048); // 8 MB
    u16* WqT   = (u16*)(hout + (i64)4096 * 512);   // [512][512]  = 0.5 MB
    u16* WkT   = WqT + (i64)512 * 512;             // 0.5 MB
    u16* WoT   = WkT + (i64)512 * 512;             // 0.5 MB
    u16* Wv2T  = WoT + (i64)512 * 512;             // [2048][1024] = 4 MB
    u16* VemT  = Wv2T + (i64)2048 * 1024;          // [512][1024]  = 1 MB

    // Pre-transpose/cast all weights to bf16 [n][k] form.
    tcast5<<<dim3(64, 32, 5), 256, 0, stream>>>(Wq, Wk, Wout, Wv2, Vemb,
                                                WqT, WkT, WoT, Wv2T, VemT);
    // qp = q@Wq+bq -> bf16; kp = k@Wk+bk -> bf16
    mgemm<true,  true ><<<dim3(4, 64), 256, 0, stream>>>(q, WqT, bq, qbf, 4096, 512, 512);
    mgemm<true,  true ><<<dim3(4, 64), 256, 0, stream>>>(k, WkT, bk, kbf, 4096, 512, 512);
    // vT[d][s] = Vemb^T @ Wv2 + bv2 -> bf16 [512][2048]
    mgemm<false, true ><<<dim3(16, 8), 256, 0, stream>>>(VemT, Wv2T, bv2, vTb, 512, 2048, 1024);
    // fused attention: writes attn (fp32 P) + hout
    attn_fused<<<dim3(1024), 256, 0, stream>>>(qbf, kbf, vTb, attn, hout);
    // out = hout@Wout + bout (fp32 out)
    mgemm<true,  false><<<dim3(4, 64), 256, 0, stream>>>(hout, WoT, bout, outp, 4096, 512, 512);
}

// Round 3
// 431.353 us; speedup vs baseline: 1.4017x; 1.0516x over previous
//
#include <hip/hip_runtime.h>
#include <math.h>

#define BB 2
#define NN 2048
#define DD 512
#define HH 8
#define HD 64
#define KML 1000

typedef long long i64;
typedef unsigned short u16;
typedef __attribute__((ext_vector_type(8))) short bf16x8;
typedef __attribute__((ext_vector_type(16))) float f32x16;

__device__ __forceinline__ u16 f2bf(float x) {
    unsigned int u = __float_as_uint(x);
    u += 0x7FFFu + ((u >> 16) & 1u);
    return (u16)(u >> 16);
}

__device__ __forceinline__ void gload_lds16(const u16* src, const u16* dst) {
    __builtin_amdgcn_global_load_lds(
        (const __attribute__((address_space(1))) unsigned int*)src,
        (__attribute__((address_space(3))) unsigned int*)dst, 16, 0, 0);
}

// ---------------------------------------------------------------------------
// Transpose-cast prepass: out[n][kp] = bf16(in[k][n]), zero-pad k >= K.
// ---------------------------------------------------------------------------
__global__ __launch_bounds__(256) void tcast5(
    const float* __restrict__ w0, const float* __restrict__ w1,
    const float* __restrict__ w2, const float* __restrict__ w3,
    const float* __restrict__ w4,
    u16* __restrict__ o0, u16* __restrict__ o1, u16* __restrict__ o2,
    u16* __restrict__ o3, u16* __restrict__ o4)
{
    const float* in; u16* out; int K, N, Kp;
    switch (blockIdx.z) {
        case 0: in = w0; out = o0; K = 512;  N = 512;  Kp = 512;  break;
        case 1: in = w1; out = o1; K = 512;  N = 512;  Kp = 512;  break;
        case 2: in = w2; out = o2; K = 512;  N = 512;  Kp = 512;  break;
        case 3: in = w3; out = o3; K = 1000; N = 2048; Kp = 1024; break;
        default:in = w4; out = o4; K = 1000; N = 512;  Kp = 1024; break;
    }
    const int n0 = blockIdx.x * 32, kp0 = blockIdx.y * 32;
    if (n0 >= N || kp0 >= Kp) return;
    __shared__ float ld[32][33];
    const int t = threadIdx.x, tx = t & 31, ty = t >> 5;
#pragma unroll
    for (int i = 0; i < 4; ++i) {
        int kk = kp0 + ty + i * 8;
        ld[ty + i * 8][tx] = (kk < K) ? in[(i64)kk * N + n0 + tx] : 0.f;
    }
    __syncthreads();
#pragma unroll
    for (int i = 0; i < 4; ++i)
        out[(i64)(n0 + ty + i * 8) * Kp + kp0 + tx] = f2bf(ld[tx][ty + i * 8]);
}

// ---------------------------------------------------------------------------
// bf16 MFMA GEMM: C[M,N] = A[M,K] @ BT[N,K]^T + bias[n].
// ---------------------------------------------------------------------------
template<bool AF32, bool BF16OUT>
__global__ __launch_bounds__(256) void mgemm(
    const void* __restrict__ Ap, const u16* __restrict__ BT,
    const float* __restrict__ bias, void* __restrict__ Cout,
    int M, int N, int K)
{
    __shared__ u16 Asl[64][40];
    __shared__ u16 Bsl[128][40];
    const int t = threadIdx.x;
    const int lane = t & 63, w = t >> 6;
    const int l31 = lane & 31, h5 = lane >> 5;
    const int wm = w >> 1, wn = w & 1;
    const int m0 = blockIdx.y * 64, n0 = blockIdx.x * 128;

    int roff[16];
#pragma unroll
    for (int r = 0; r < 16; ++r) roff[r] = (r & 3) + 8 * (r >> 2) + 4 * h5;

    f32x16 acc[2];
#pragma unroll
    for (int nt = 0; nt < 2; ++nt)
#pragma unroll
        for (int r = 0; r < 16; ++r) acc[nt][r] = 0.f;

    for (int k0 = 0; k0 < K; k0 += 32) {
        __syncthreads();
        {   // A tile: 64 x 32
            int row = t >> 2, kc = (t & 3) * 8;
            if (AF32) {
                const float* A = (const float*)Ap;
                const float* src = A + (i64)(m0 + row) * K + k0 + kc;
                float4 v0 = *(const float4*)src;
                float4 v1 = *(const float4*)(src + 4);
                bf16x8 p;
                p[0] = (short)f2bf(v0.x); p[1] = (short)f2bf(v0.y);
                p[2] = (short)f2bf(v0.z); p[3] = (short)f2bf(v0.w);
                p[4] = (short)f2bf(v1.x); p[5] = (short)f2bf(v1.y);
                p[6] = (short)f2bf(v1.z); p[7] = (short)f2bf(v1.w);
                *(bf16x8*)&Asl[row][kc] = p;
            } else {
                const u16* A = (const u16*)Ap;
                *(bf16x8*)&Asl[row][kc] =
                    *(const bf16x8*)(A + (i64)(m0 + row) * K + k0 + kc);
            }
        }
        {   // B tile: 128 x 32 (bf16, k-contiguous)
            int row = t >> 1, kc = (t & 1) * 16;
            const u16* src = BT + (i64)(n0 + row) * K + k0 + kc;
            *(bf16x8*)&Bsl[row][kc]     = *(const bf16x8*)src;
            *(bf16x8*)&Bsl[row][kc + 8] = *(const bf16x8*)(src + 8);
        }
        __syncthreads();
#pragma unroll
        for (int kk = 0; kk < 2; ++kk) {
            bf16x8 af = *(const bf16x8*)&Asl[wm * 32 + l31][kk * 16 + h5 * 8];
#pragma unroll
            for (int nt = 0; nt < 2; ++nt) {
                bf16x8 bf = *(const bf16x8*)&Bsl[wn * 64 + nt * 32 + l31][kk * 16 + h5 * 8];
                acc[nt] = __builtin_amdgcn_mfma_f32_32x32x16_bf16(af, bf, acc[nt], 0, 0, 0);
            }
        }
    }
#pragma unroll
    for (int nt = 0; nt < 2; ++nt) {
        int col = n0 + wn * 64 + nt * 32 + l31;
        float bv = bias[col];
#pragma unroll
        for (int r = 0; r < 16; ++r) {
            int row = m0 + wm * 32 + roff[r];
            float v = acc[nt][r] + bv;
            if (BF16OUT) ((u16*)Cout)[(i64)row * N + col] = f2bf(v);
            else         ((float*)Cout)[(i64)row * N + col] = v;
        }
    }
}

// ---------------------------------------------------------------------------
// Fused flash-style attention with P materialization.
// Per block: 32 q-rows of one (b,h); 4 waves partition 128-col super-chunks.
// K/V staged to LDS via global_load_lds (linear dst, inverse-XOR-swizzled
// per-lane source), XOR-swizzled ds_read_b128 fragment reads, double-buffered
// 2-phase schedule (stage c+1 before computing c; __syncthreads = drain).
// Phase 1: row sums of exp2(S*SC).  Phase 2: P store (fp32) + PV MFMA.
// ---------------------------------------------------------------------------
__global__ __launch_bounds__(256, 2) void attn_fused(
    const u16* __restrict__ qbf,   // [4096][512] bf16
    const u16* __restrict__ kbf,   // [4096][512] bf16
    const u16* __restrict__ vTb,   // [512][2048] bf16  (d-major: vT[d][j])
    float* __restrict__ attn,      // [16][2048][2048] fp32
    float* __restrict__ hout)      // [2][2048][512] fp32
{
    // pool[buf]: K tile [128 rows][8 x 16B blocks] u16 [0,8192),
    //            V tile [64 d-rows][16 x 16B blocks] u16 [8192,16384)
    __shared__ __align__(16) u16 pool[2][16384];      // 64 KB
    __shared__ u16   Plds[4][32][40];                 // 10 KB
    __shared__ float redL[4][32];
    __shared__ float ilsh[32];
    float* Olds = (float*)&pool[0][0];                // [4][64][36] f32, aliased

    const int t    = threadIdx.x;
    const int lane = t & 63;
    const int w    = t >> 6;
    const int l31  = lane & 31;
    const int h5   = lane >> 5;

    const int bid = blockIdx.x;
    const int swz = (bid & 7) * 128 + (bid >> 3);
    const int bx  = swz & 63;
    const int bh  = swz >> 6;
    const int b   = bh >> 3, h = bh & 7;
    const int i0  = bx * 32;
    const float SC = 0.18033688011112042f;   // 0.125 * log2(e)

    const u16* qb = qbf + (i64)(b * NN + i0) * DD + h * HD;
    const u16* kb = kbf + (i64)(b * NN) * DD + h * HD;
    const u16* vb = vTb + (i64)h * HD * NN;
    float* Pg = attn + (i64)bh * NN * NN;

    int roff[16];
#pragma unroll
    for (int r = 0; r < 16; ++r) roff[r] = (r & 3) + 8 * (r >> 2) + 4 * h5;

    // ---- stage helpers (per wave; wave w owns K rows [w*32,w*32+32),
    //      V d-rows [w*16,w*16+16)) ----
    auto stageK = [&](int buf, int c) {
#pragma unroll
        for (int i = 0; i < 4; ++i) {
            int e   = i * 64 + lane;
            int row = w * 32 + (e >> 3);
            int blk = e & 7;
            const u16* src = kb + (i64)(c * 128 + row) * DD + ((blk ^ (row & 7)) * 8);
            const u16* dst = &pool[buf][(w * 256 + i * 64) * 8];
            gload_lds16(src, dst);
        }
    };
    auto stageV = [&](int buf, int c) {
#pragma unroll
        for (int i = 0; i < 4; ++i) {
            int e  = i * 64 + lane;
            int d  = w * 16 + (e >> 4);
            int jb = e & 15;
            const u16* src = vb + (i64)d * NN + c * 128 + ((jb ^ (d & 15)) * 8);
            const u16* dst = &pool[buf][8192 + (w * 256 + i * 64) * 8];
            gload_lds16(src, dst);
        }
    };

    // ---- Q fragments ----
    bf16x8 qa[4];
#pragma unroll
    for (int f = 0; f < 4; ++f)
        qa[f] = *(const bf16x8*)(qb + (i64)l31 * DD + f * 16 + h5 * 8);

    // ================= phase 1: row sums =================
    stageK(0, 0);
    __syncthreads();

    float lsum[16];
#pragma unroll
    for (int r = 0; r < 16; ++r) lsum[r] = 0.f;

    for (int c = 0; c < 16; ++c) {
        if (c < 15) stageK((c + 1) & 1, c + 1);
        const u16* Kc = &pool[c & 1][0];
        const int j0 = c * 128 + w * 32;
        bf16x8 kf[4];
#pragma unroll
        for (int f = 0; f < 4; ++f) {
            int blk = (f * 2 + h5) ^ (l31 & 7);
            kf[f] = *(const bf16x8*)&Kc[((w * 32 + l31) * 8 + blk) * 8];
        }
        f32x16 s;
#pragma unroll
        for (int r = 0; r < 16; ++r) s[r] = 0.f;
#pragma unroll
        for (int f = 0; f < 4; ++f)
            s = __builtin_amdgcn_mfma_f32_32x32x16_bf16(qa[f], kf[f], s, 0, 0, 0);
        const int gj = j0 + l31;
        const bool hasband = (j0 >= i0 - 34) && (j0 <= i0 + 34);
        if (hasband) {
#pragma unroll
            for (int r = 0; r < 16; ++r) {
                int d = (i0 + roff[r]) - gj;
                float e = (d >= -3 && d <= 3) ? 0.f
                        : __builtin_amdgcn_exp2f(s[r] * SC);
                lsum[r] += e;
            }
        } else {
#pragma unroll
            for (int r = 0; r < 16; ++r)
                lsum[r] += __builtin_amdgcn_exp2f(s[r] * SC);
        }
        __syncthreads();
    }

    // stage phase-2 c=0 early (latency hides under the L reduction)
    stageK(0, 0);
    stageV(0, 0);

#pragma unroll
    for (int r = 0; r < 16; ++r) {
        float v = lsum[r];
        v += __shfl_xor(v, 1);
        v += __shfl_xor(v, 2);
        v += __shfl_xor(v, 4);
        v += __shfl_xor(v, 8);
        v += __shfl_xor(v, 16);
        lsum[r] = v;
    }
    if (l31 == 0) {
#pragma unroll
        for (int r = 0; r < 16; ++r) redL[w][roff[r]] = lsum[r];
    }
    __syncthreads();
    if (t < 32) ilsh[t] = 1.f / (redL[0][t] + redL[1][t] + redL[2][t] + redL[3][t]);
    __syncthreads();
    float ilv[16];
#pragma unroll
    for (int r = 0; r < 16; ++r) ilv[r] = ilsh[roff[r]];

    // ================= phase 2: P store + PV =================
    f32x16 oacc[2];
#pragma unroll
    for (int dt = 0; dt < 2; ++dt)
#pragma unroll
        for (int r = 0; r < 16; ++r) oacc[dt][r] = 0.f;

    for (int c = 0; c < 16; ++c) {
        if (c < 15) { stageK((c + 1) & 1, c + 1); stageV((c + 1) & 1, c + 1); }
        const u16* Kc = &pool[c & 1][0];
        const u16* Vc = &pool[c & 1][8192];
        const int j0 = c * 128 + w * 32;
        bf16x8 kf[4];
#pragma unroll
        for (int f = 0; f < 4; ++f) {
            int blk = (f * 2 + h5) ^ (l31 & 7);
            kf[f] = *(const bf16x8*)&Kc[((w * 32 + l31) * 8 + blk) * 8];
        }
        f32x16 s;
#pragma unroll
        for (int r = 0; r < 16; ++r) s[r] = 0.f;
#pragma unroll
        for (int f = 0; f < 4; ++f)
            s = __builtin_amdgcn_mfma_f32_32x32x16_bf16(qa[f], kf[f], s, 0, 0, 0);
        const int gj = j0 + l31;
        const bool hasband = (j0 >= i0 - 34) && (j0 <= i0 + 34);
        if (hasband) {
#pragma unroll
            for (int r = 0; r < 16; ++r) {
                int gi = i0 + roff[r];
                int d  = gi - gj;
                float p = (d >= -3 && d <= 3) ? 0.f
                        : __builtin_amdgcn_exp2f(s[r] * SC) * ilv[r];
                Pg[(i64)gi * NN + gj] = p;
                Plds[w][roff[r]][l31] = f2bf(p);
            }
        } else {
#pragma unroll
            for (int r = 0; r < 16; ++r) {
                int gi = i0 + roff[r];
                float p = __builtin_amdgcn_exp2f(s[r] * SC) * ilv[r];
                Pg[(i64)gi * NN + gj] = p;
                Plds[w][roff[r]][l31] = f2bf(p);
            }
        }
#pragma unroll
        for (int jt = 0; jt < 2; ++jt) {
            bf16x8 pa = *(const bf16x8*)&Plds[w][l31][jt * 16 + h5 * 8];
#pragma unroll
            for (int dt = 0; dt < 2; ++dt) {
                int vblk = (w * 4 + jt * 2 + h5) ^ (l31 & 15);
                bf16x8 vf = *(const bf16x8*)&Vc[((dt * 32 + l31) * 16 + vblk) * 8];
                oacc[dt] = __builtin_amdgcn_mfma_f32_32x32x16_bf16(pa, vf, oacc[dt], 0, 0, 0);
            }
        }
        __syncthreads();
    }

    // ---- cross-wave O reduction (Olds aliases pool; all reads drained) ----
#pragma unroll
    for (int dt = 0; dt < 2; ++dt) {
        const int d = dt * 32 + l31;
#pragma unroll
        for (int g = 0; g < 4; ++g) {
            float4 o4 = make_float4(oacc[dt][g * 4 + 0], oacc[dt][g * 4 + 1],
                                    oacc[dt][g * 4 + 2], oacc[dt][g * 4 + 3]);
            *(float4*)&Olds[(w * 64 + d) * 36 + g * 8 + 4 * h5] = o4;
        }
    }
    __syncthreads();
#pragma unroll
    for (int it = 0; it < 8; ++it) {
        int d = t & 63, row = (t >> 6) + it * 4;
        float v = Olds[(0 * 64 + d) * 36 + row] + Olds[(1 * 64 + d) * 36 + row]
                + Olds[(2 * 64 + d) * 36 + row] + Olds[(3 * 64 + d) * 36 + row];
        hout[(i64)(b * NN + i0 + row) * DD + h * HD + d] = v;
    }
}

// ---------------------------------------------------------------------------
extern "C" void kernel_launch(void* const* d_in, const int* in_sizes, int n_in,
                              void* d_out, int out_size, void* d_ws, size_t ws_size,
                              hipStream_t stream)
{
    const float* q    = (const float*)d_in[0];
    const float* k    = (const float*)d_in[1];
    const float* Wq   = (const float*)d_in[3];
    const float* bq   = (const float*)d_in[4];
    const float* Wk   = (const float*)d_in[5];
    const float* bk   = (const float*)d_in[6];
    const float* Vemb = (const float*)d_in[7];
    const float* Wv2  = (const float*)d_in[8];
    const float* bv2  = (const float*)d_in[9];
    const float* Wout = (const float*)d_in[10];
    const float* bout = (const float*)d_in[11];

    float* outp = (float*)d_out;                   // [2,2048,512]
    float* attn = outp + (i64)BB * NN * DD;        // [2,8,2048,2048]

    u16* qbf   = (u16*)d_ws;                       // 4 MB
    u16* kbf   = qbf + (i64)4096 * 512;            // 4 MB
    u16* vTb   = kbf + (i64)4096 * 512;            // [512][2048] = 2 MB
    float* hout = (float*)(vTb + (i64)512 * 2048); // 8 MB
    u16* WqT   = (u16*)(hout + (i64)4096 * 512);   // [512][512]
    u16* WkT   = WqT + (i64)512 * 512;
    u16* WoT   = WkT + (i64)512 * 512;
    u16* Wv2T  = WoT + (i64)512 * 512;             // [2048][1024]
    u16* VemT  = Wv2T + (i64)2048 * 1024;          // [512][1024]

    tcast5<<<dim3(64, 32, 5), 256, 0, stream>>>(Wq, Wk, Wout, Wv2, Vemb,
                                                WqT, WkT, WoT, Wv2T, VemT);
    mgemm<true,  true ><<<dim3(4, 64), 256, 0, stream>>>(q, WqT, bq, qbf, 4096, 512, 512);
    mgemm<true,  true ><<<dim3(4, 64), 256, 0, stream>>>(k, WkT, bk, kbf, 4096, 512, 512);
    mgemm<false, true ><<<dim3(16, 8), 256, 0, stream>>>(VemT, Wv2T, bv2, vTb, 512, 2048, 1024);
    attn_fused<<<dim3(1024), 256, 0, stream>>>(qbf, kbf, vTb, attn, hout);
    mgemm<true,  false><<<dim3(4, 64), 256, 0, stream>>>(hout, WoT, bout, outp, 4096, 512, 512);
}